// Round 14
// baseline (47.245 us; speedup 1.0000x reference)
//
#include <hip/hip_runtime.h>
#include <hip/hip_bf16.h>
#include <math.h>

typedef __attribute__((ext_vector_type(8))) short bf16x8;
typedef __attribute__((ext_vector_type(8))) unsigned short u16x8;
typedef __attribute__((ext_vector_type(4))) float f32x4;

__device__ __forceinline__ unsigned short f2bf(float f) {
    return __builtin_bit_cast(unsigned short, __float2bfloat16(f));
}

__device__ __forceinline__ float bf2f(unsigned short u) {
    unsigned int x = (unsigned int)u << 16;
    return __builtin_bit_cast(float, x);
}

__device__ __forceinline__ float sigmoidf_(float v) {
    return 1.f / (1.f + __expf(-v));
}

struct StageRegs { float4 w0, w1, x0, x1; };

// Fused convert+GEMM.  y4[b][m][p] (bf16) = bias[m] + sum_k w[m][k]*x4[b][k][p].
// Tile 128m x 64p (x4 re-read 8x -> 4x vs r13; staging traffic 262->195 MB),
// full K=2048, BK=64.  1024 threads = 16 waves, each a 16m x 32p sub-tile.
// T14 distance-2 register pipeline, one barrier per K-tile.  XOR-swizzled
// LDS tiles: elem (r,k) at r*64 + ((k>>3)^(r&7))*8 + (k&7) shorts.
// Grid 128; blockIdx&7 = XCD = batch b.
__global__ __launch_bounds__(1024) void gemm_fused(
    const float* __restrict__ x4, const float* __restrict__ w,
    const float* __restrict__ bias, unsigned short* __restrict__ y4,
    float* __restrict__ chanpart)
{
    __shared__ short As[2][8192];   // [buf][128m x 64k] swizzled
    __shared__ short Bs[2][4096];   // [buf][64p x 64k] swizzled

    const int tid = threadIdx.x;
    const int wave = tid >> 6, lane = tid & 63;
    const int wm = wave >> 1, wn = wave & 1;     // wm 0..7 (16m), wn 0..1 (32p)
    const int lr = lane & 15, lh = lane >> 4;

    const int flat = blockIdx.x;
    const int b = flat & 7;              // XCD-aligned batch
    const int j = flat >> 3;             // 0..15
    const int mt = j & 3;                // 0..3  (128-row chunk of M=512)
    const int nq = j >> 2;               // 0..3  (64-col chunk of one batch)

    // staging roles
    const int ar = tid >> 3, ac = tid & 7;          // A: row 0..127, k-chunk 0..7
    const bool doB = (tid < 512);                   // waves 0..7 stage B
    const int ku = (tid & 511) >> 4, xp4 = tid & 15; // B: k-pair 0..31, p-quad 0..15

    const float* wbase = w + (size_t)(mt * 128 + ar) * 2048 + ac * 8;
    const float* xbase = x4 + ((size_t)b * 2048 + 2 * ku) * 256 + nq * 64 + xp4 * 4;

#define LOADT(R, t) {                                                         \
        (R).w0 = *(const float4*)(wbase + (t) * 64);                          \
        (R).w1 = *(const float4*)(wbase + (t) * 64 + 4);                      \
        if (doB) {                                                            \
            (R).x0 = *(const float4*)(xbase + (size_t)(t) * 64 * 256);        \
            (R).x1 = *(const float4*)(xbase + (size_t)(t) * 64 * 256 + 256);  \
        } }
#define WRITET(buf, R) {                                                      \
        u16x8 o;                                                              \
        o[0] = f2bf((R).w0.x); o[1] = f2bf((R).w0.y);                         \
        o[2] = f2bf((R).w0.z); o[3] = f2bf((R).w0.w);                         \
        o[4] = f2bf((R).w1.x); o[5] = f2bf((R).w1.y);                         \
        o[6] = f2bf((R).w1.z); o[7] = f2bf((R).w1.w);                         \
        *(u16x8*)(&As[buf][ar * 64 + ((ac ^ (ar & 7)) * 8)]) = o;             \
        if (doB) {                                                            \
            unsigned int pk0 = f2bf((R).x0.x) | ((unsigned int)f2bf((R).x1.x) << 16); \
            unsigned int pk1 = f2bf((R).x0.y) | ((unsigned int)f2bf((R).x1.y) << 16); \
            unsigned int pk2 = f2bf((R).x0.z) | ((unsigned int)f2bf((R).x1.z) << 16); \
            unsigned int pk3 = f2bf((R).x0.w) | ((unsigned int)f2bf((R).x1.w) << 16); \
            unsigned int* bs32 = (unsigned int*)&Bs[buf][0];                  \
            { int p = xp4 * 4 + 0;                                            \
              bs32[p * 32 + ((ku >> 2) ^ (p & 7)) * 4 + (ku & 3)] = pk0; }    \
            { int p = xp4 * 4 + 1;                                            \
              bs32[p * 32 + ((ku >> 2) ^ (p & 7)) * 4 + (ku & 3)] = pk1; }    \
            { int p = xp4 * 4 + 2;                                            \
              bs32[p * 32 + ((ku >> 2) ^ (p & 7)) * 4 + (ku & 3)] = pk2; }    \
            { int p = xp4 * 4 + 3;                                            \
              bs32[p * 32 + ((ku >> 2) ^ (p & 7)) * 4 + (ku & 3)] = pk3; }    \
        } }
#define MFMA_TILE(cur) {                                                      \
        _Pragma("unroll")                                                     \
        for (int kc = 0; kc < 2; ++kc) {                                      \
            const int ch = kc * 4 + lh;                                       \
            int rA  = wm * 16 + lr;                                           \
            int rB0 = wn * 32 + lr, rB1 = rB0 + 16;                           \
            bf16x8 a0 = *(const bf16x8*)(&As[cur][rA  * 64 + ((ch ^ (rA  & 7)) * 8)]); \
            bf16x8 b0 = *(const bf16x8*)(&Bs[cur][rB0 * 64 + ((ch ^ (rB0 & 7)) * 8)]); \
            bf16x8 b1 = *(const bf16x8*)(&Bs[cur][rB1 * 64 + ((ch ^ (rB1 & 7)) * 8)]); \
            acc0 = __builtin_amdgcn_mfma_f32_16x16x32_bf16(a0, b0, acc0, 0, 0, 0); \
            acc1 = __builtin_amdgcn_mfma_f32_16x16x32_bf16(a0, b1, acc1, 0, 0, 0); \
        } }

    StageRegs Ra, Rb;
    // Prologue: tile0 -> buf0 (via Ra), tile1 -> Rb, tile2 -> Ra (in flight)
    LOADT(Ra, 0);
    WRITET(0, Ra);
    LOADT(Rb, 1);
    LOADT(Ra, 2);
    __syncthreads();

    f32x4 acc0 = {}, acc1 = {};
    for (int t = 0; t < 32; t += 2) {
        // even: consume buf0 (tile t); write buf1 <- tile t+1 (Rb, loaded 2
        // iters ago, vmcnt satisfied); issue load tile t+3 -> Rb
        WRITET(1, Rb);
        if (t < 29) LOADT(Rb, t + 3);
        MFMA_TILE(0);
        __syncthreads();
        // odd: consume buf1 (tile t+1); write buf0 <- tile t+2 (Ra); load t+4
        if (t < 30) {
            WRITET(0, Ra);
            if (t < 28) LOADT(Ra, t + 4);
        }
        MFMA_TILE(1);
        __syncthreads();
    }
#undef LOADT
#undef WRITET
#undef MFMA_TILE

    unsigned short* yb = y4 + ((size_t)b * 512 + mt * 128) * 256 + nq * 64;
#pragma unroll
    for (int rr = 0; rr < 4; ++rr) {
        const int m = wm * 16 + lh * 4 + rr;      // within 128-row tile
        const float bv = bias[mt * 128 + m];
        yb[m * 256 + wn * 32 + lr]      = f2bf(acc0[rr] + bv);
        yb[m * 256 + wn * 32 + 16 + lr] = f2bf(acc1[rr] + bv);
        // wave-local sum over its 32 n positions (fp32, unchanged)
        float s = acc0[rr] + acc1[rr];
        s += __shfl_xor(s, 1);
        s += __shfl_xor(s, 2);
        s += __shfl_xor(s, 4);
        s += __shfl_xor(s, 8);
        if (lr == 0)
            chanpart[(size_t)(b * 512 + mt * 128 + m) * 8 + nq * 2 + wn] = s + 32.f * bv;
    }
}

// Per (bg, p-chunk of 32): fc1+fc2 (redundant per chunk, cheap), sa dot over
// 256 channels, deterministic gsum partial.  512 blocks x 256 threads.
// y4 is bf16; slice staged into LDS as fp32.
__global__ __launch_bounds__(256) void sa_kernel(
    const unsigned short* __restrict__ y4, const float* __restrict__ chanpart,
    const float* __restrict__ fc1w, const float* __restrict__ fc1b,
    const float* __restrict__ fc2w, const float* __restrict__ fc2b,
    const float* __restrict__ saw, const float* __restrict__ sab,
    float* __restrict__ ca, float* __restrict__ sa, float* __restrict__ gsums)
{
    const int blk = blockIdx.x;
    const int bg = blk >> 3, pc = blk & 7;
    const int b = bg >> 3, g = bg & 7;
    const int tid = threadIdx.x;
    const unsigned short* xg = y4 + ((size_t)b * 512 + (g & 1) * 256) * 256 + pc * 32;

    __shared__ float xl[256][32];
    __shared__ float avgs[256], red[256], hs[64], cas[256], caws[256], sas[32];

    // stage y4 slice [256c][32p] (bf16 -> fp32)
#pragma unroll
    for (int i = 0; i < 4; ++i) {
        int f = i * 256 + tid;            // ushort8 chunk id, 1024 total
        int c = f >> 2, jj = f & 3;
        u16x8 v = *(const u16x8*)(xg + c * 256 + jj * 8);
#pragma unroll
        for (int e = 0; e < 8; ++e) xl[c][jj * 8 + e] = bf2f(v[e]);
    }
    {
        const float* cpp = chanpart + (size_t)(b * 512 + (g & 1) * 256 + tid) * 8;
        float cp = 0.f;
#pragma unroll
        for (int i = 0; i < 8; ++i) cp += cpp[i];
        avgs[tid] = cp * (1.f / 256.f);
    }
    __syncthreads();
    // fc1: 256 -> 64, relu
    {
        int o = tid & 63, seg = tid >> 6;
        const float* wr = fc1w + (g * 64 + o) * 256 + seg * 64;
        const float* av = avgs + seg * 64;
        float s = 0.f;
#pragma unroll
        for (int i = 0; i < 64; ++i) s = fmaf(av[i], wr[i], s);
        red[tid] = s;
    }
    __syncthreads();
    if (tid < 64) {
        float s = fc1b[g * 64 + tid] + red[tid] + red[64 + tid] + red[128 + tid] + red[192 + tid];
        hs[tid] = fmaxf(s, 0.f);
    }
    __syncthreads();
    // fc2: 64 -> 256, sigmoid
    {
        const float* wr = fc2w + (g * 256 + tid) * 64;
        float s = fc2b[g * 256 + tid];
#pragma unroll
        for (int i = 0; i < 64; ++i) s = fmaf(hs[i], wr[i], s);
        float v = sigmoidf_(s);
        cas[tid] = v;
        caws[tid] = v * saw[g * 256 + tid];
        if (pc == 0) ca[bg * 256 + tid] = v;
    }
    __syncthreads();
    // sa dot over channels for 32 positions (from LDS)
    const int p_l = tid & 31, seg8 = tid >> 5;
    {
        float s = 0.f;
#pragma unroll
        for (int i = 0; i < 32; ++i) {
            int c = seg8 * 32 + i;
            s = fmaf(xl[c][p_l], caws[c], s);
        }
        red[tid] = s;
    }
    __syncthreads();
    if (tid < 32) {
        float s = sab[g];
#pragma unroll
        for (int k = 0; k < 8; ++k) s += red[k * 32 + tid];
        float v = sigmoidf_(s);
        sas[tid] = v;
        sa[bg * 256 + pc * 32 + tid] = v;
    }
    __syncthreads();
    // gsum partial: sum sigmoid(x*ca*sa) over this chunk's 32p x 256c
    {
        float sv = sas[p_l];
        float s = 0.f;
#pragma unroll
        for (int i = 0; i < 32; ++i) {
            int c = seg8 * 32 + i;
            s += sigmoidf_(xl[c][p_l] * cas[c] * sv);
        }
        red[tid] = s;
    }
    __syncthreads();
    for (int off = 128; off > 0; off >>= 1) {
        if (tid < off) red[tid] += red[tid + off];
        __syncthreads();
    }
    if (tid == 0) gsums[blk] = red[0];
}

// out = x*(1+mask); mask = (y>mean)?1:y, y = sigmoid(x*ca*sa).
// Dedup: each y4 element (bf16) read ONCE, expanded to its 4 output channels
// (g = parity, parity+2, parity+4, parity+6).  262144 threads total.
__global__ __launch_bounds__(256) void final_kernel(
    const unsigned short* __restrict__ y4, const float* __restrict__ ca,
    const float* __restrict__ sa, const float* __restrict__ gsums,
    float* __restrict__ out)
{
    int f = blockIdx.x * 256 + threadIdx.x;   // 0..262143: (b, c', p4)
    int p4 = f & 63;                          // quad index within row
    int cp = (f >> 6) & 511;                  // unique y4 channel 0..511
    int b  = f >> 15;                         // batch 0..7
    int par = cp >> 8, c = cp & 255;
    const ushort4 xu = *(const ushort4*)(y4 + ((size_t)b * 512 + cp) * 256 + p4 * 4);
    const float x0 = bf2f(xu.x), x1 = bf2f(xu.y), x2 = bf2f(xu.z), x3 = bf2f(xu.w);
#pragma unroll
    for (int gg = 0; gg < 4; ++gg) {
        const int g = par + gg * 2;
        const int bg = b * 8 + g;
        const float cav = ca[bg * 256 + c];
        const float4 sv = *(const float4*)(sa + bg * 256 + p4 * 4);
        float msum = 0.f;
#pragma unroll
        for (int i = 0; i < 8; ++i) msum += gsums[bg * 8 + i];
        const float mean = msum * (1.f / 65536.f);
        float4 o;
#define DOLANE(OX, XV, SX) { float yv = sigmoidf_((XV) * cav * sv.SX); \
        float mk = (yv > mean) ? 1.f : yv; o.OX = (XV) * (1.f + mk); }
        DOLANE(x, x0, x) DOLANE(y, x1, y) DOLANE(z, x2, z) DOLANE(w, x3, w)
#undef DOLANE
        *(float4*)(out + ((size_t)b * 2048 + g * 256 + c) * 256 + p4 * 4) = o;
    }
}

extern "C" void kernel_launch(void* const* d_in, const int* in_sizes, int n_in,
                              void* d_out, int out_size, void* d_ws, size_t ws_size,
                              hipStream_t stream) {
    const float* x4   = (const float*)d_in[3];
    const float* w4   = (const float*)d_in[10];
    const float* b4   = (const float*)d_in[11];
    const float* fc1w = (const float*)d_in[12];
    const float* fc1b = (const float*)d_in[13];
    const float* fc2w = (const float*)d_in[14];
    const float* fc2b = (const float*)d_in[15];
    const float* saw  = (const float*)d_in[16];
    const float* sab  = (const float*)d_in[17];
    float* out = (float*)d_out;

    float* ws = (float*)d_ws;
    unsigned short* y4 = (unsigned short*)ws;  // 1048576 bf16 (= 524288 floats)
    float* ca       = ws + 524288;           // 16384
    float* saBuf    = ws + 540672;           // 16384
    float* gsums    = ws + 557056;           // 512
    float* chanpart = ws + 557568;           // 32768

    gemm_fused<<<dim3(128), dim3(1024), 0, stream>>>(x4, w4, b4, y4, chanpart);
    sa_kernel<<<dim3(512), dim3(256), 0, stream>>>(y4, chanpart, fc1w, fc1b, fc2w, fc2b,
                                                   saw, sab, ca, saBuf, gsums);
    final_kernel<<<dim3(1024), dim3(256), 0, stream>>>(y4, ca, saBuf, gsums, out);
}

// Round 15
// 43.034 us; speedup vs baseline: 1.0978x; 1.0978x over previous
//
#include <hip/hip_runtime.h>
#include <hip/hip_bf16.h>
#include <math.h>

typedef __attribute__((ext_vector_type(8))) short bf16x8;
typedef __attribute__((ext_vector_type(8))) unsigned short u16x8;
typedef __attribute__((ext_vector_type(4))) float f32x4;

__device__ __forceinline__ unsigned short f2bf(float f) {
    return __builtin_bit_cast(unsigned short, __float2bfloat16(f));
}

__device__ __forceinline__ float bf2f(unsigned short u) {
    unsigned int x = (unsigned int)u << 16;
    return __builtin_bit_cast(float, x);
}

__device__ __forceinline__ float sigmoidf_(float v) {
    return 1.f / (1.f + __expf(-v));
}

struct StageRegs { float4 w0, w1, x0, x1; };

// Fused convert+GEMM (r13-proven, best: 43.2 us).  y4[b][m][p] (bf16) =
// bias[m] + sum_k w[m][k]*x4[b][k][p].  Tile 64m x 64p, full K=2048, BK=64.
// 512 threads = 8 waves, each a 16m x 32p sub-tile.  T14 distance-2 register
// pipeline, one barrier per K-tile.  XOR-swizzled LDS tiles: elem (r,k) at
// r*64 + ((k>>3)^(r&7))*8 + (k&7) shorts.  Grid 256 (1 block/CU — measured
// optimum: r7's 4/CU (+2x traffic) and r14's 0.5/CU (-25% traffic) both lose).
// blockIdx&7 = XCD = batch b.
__global__ __launch_bounds__(512) void gemm_fused(
    const float* __restrict__ x4, const float* __restrict__ w,
    const float* __restrict__ bias, unsigned short* __restrict__ y4,
    float* __restrict__ chanpart)
{
    __shared__ short As[2][4096];   // [buf][64m x 64k] swizzled
    __shared__ short Bs[2][4096];   // [buf][64p x 64k] swizzled

    const int tid = threadIdx.x;
    const int wave = tid >> 6, lane = tid & 63;
    const int wm = wave >> 1, wn = wave & 1;     // wm 0..3 (16m), wn 0..1 (32p)
    const int lr = lane & 15, lh = lane >> 4;

    const int flat = blockIdx.x;
    const int b = flat & 7;              // XCD-aligned batch
    const int j = flat >> 3;
    const int mt = j & 7;                // 0..7  (64-row chunk of M=512)
    const int nq = j >> 3;               // 0..3  (64-col chunk of one batch)

    // staging roles (512 threads)
    const int ar = tid >> 3, ac = tid & 7;    // A: row 0..63, k-chunk(8) 0..7
    const int ku = tid >> 4, xp4 = tid & 15;  // B: k-pair 0..31, p-quad 0..15

    const float* wbase = w + (size_t)(mt * 64 + ar) * 2048 + ac * 8;
    const float* xbase = x4 + ((size_t)b * 2048 + 2 * ku) * 256 + nq * 64 + xp4 * 4;

#define LOADT(R, t) {                                                         \
        (R).w0 = *(const float4*)(wbase + (t) * 64);                          \
        (R).w1 = *(const float4*)(wbase + (t) * 64 + 4);                      \
        (R).x0 = *(const float4*)(xbase + (size_t)(t) * 64 * 256);            \
        (R).x1 = *(const float4*)(xbase + (size_t)(t) * 64 * 256 + 256); }
#define WRITET(buf, R) {                                                      \
        u16x8 o;                                                              \
        o[0] = f2bf((R).w0.x); o[1] = f2bf((R).w0.y);                         \
        o[2] = f2bf((R).w0.z); o[3] = f2bf((R).w0.w);                         \
        o[4] = f2bf((R).w1.x); o[5] = f2bf((R).w1.y);                         \
        o[6] = f2bf((R).w1.z); o[7] = f2bf((R).w1.w);                         \
        *(u16x8*)(&As[buf][ar * 64 + ((ac ^ (ar & 7)) * 8)]) = o;             \
        unsigned int pk0 = f2bf((R).x0.x) | ((unsigned int)f2bf((R).x1.x) << 16); \
        unsigned int pk1 = f2bf((R).x0.y) | ((unsigned int)f2bf((R).x1.y) << 16); \
        unsigned int pk2 = f2bf((R).x0.z) | ((unsigned int)f2bf((R).x1.z) << 16); \
        unsigned int pk3 = f2bf((R).x0.w) | ((unsigned int)f2bf((R).x1.w) << 16); \
        unsigned int* bs32 = (unsigned int*)&Bs[buf][0];                      \
        { int p = xp4 * 4 + 0;                                                \
          bs32[p * 32 + ((ku >> 2) ^ (p & 7)) * 4 + (ku & 3)] = pk0; }        \
        { int p = xp4 * 4 + 1;                                                \
          bs32[p * 32 + ((ku >> 2) ^ (p & 7)) * 4 + (ku & 3)] = pk1; }        \
        { int p = xp4 * 4 + 2;                                                \
          bs32[p * 32 + ((ku >> 2) ^ (p & 7)) * 4 + (ku & 3)] = pk2; }        \
        { int p = xp4 * 4 + 3;                                                \
          bs32[p * 32 + ((ku >> 2) ^ (p & 7)) * 4 + (ku & 3)] = pk3; } }
#define MFMA_TILE(cur) {                                                      \
        _Pragma("unroll")                                                     \
        for (int kc = 0; kc < 2; ++kc) {                                      \
            const int ch = kc * 4 + lh;                                       \
            int rA  = wm * 16 + lr;                                           \
            int rB0 = wn * 32 + lr, rB1 = rB0 + 16;                           \
            bf16x8 a0 = *(const bf16x8*)(&As[cur][rA  * 64 + ((ch ^ (rA  & 7)) * 8)]); \
            bf16x8 b0 = *(const bf16x8*)(&Bs[cur][rB0 * 64 + ((ch ^ (rB0 & 7)) * 8)]); \
            bf16x8 b1 = *(const bf16x8*)(&Bs[cur][rB1 * 64 + ((ch ^ (rB1 & 7)) * 8)]); \
            acc0 = __builtin_amdgcn_mfma_f32_16x16x32_bf16(a0, b0, acc0, 0, 0, 0); \
            acc1 = __builtin_amdgcn_mfma_f32_16x16x32_bf16(a0, b1, acc1, 0, 0, 0); \
        } }

    StageRegs Ra, Rb;
    // Prologue: tile0 -> buf0 (via Ra), tile1 -> Rb, tile2 -> Ra (in flight)
    LOADT(Ra, 0);
    WRITET(0, Ra);
    LOADT(Rb, 1);
    LOADT(Ra, 2);
    __syncthreads();

    f32x4 acc0 = {}, acc1 = {};
    for (int t = 0; t < 32; t += 2) {
        // even: consume buf0 (tile t); write buf1 <- tile t+1 (Rb, loaded 2
        // iters ago, vmcnt satisfied); issue load tile t+3 -> Rb
        WRITET(1, Rb);
        if (t < 29) LOADT(Rb, t + 3);
        MFMA_TILE(0);
        __syncthreads();
        // odd: consume buf1 (tile t+1); write buf0 <- tile t+2 (Ra); load t+4
        if (t < 30) {
            WRITET(0, Ra);
            if (t < 28) LOADT(Ra, t + 4);
        }
        MFMA_TILE(1);
        __syncthreads();
    }
#undef LOADT
#undef WRITET
#undef MFMA_TILE

    unsigned short* yb = y4 + ((size_t)b * 512 + mt * 64) * 256 + nq * 64;
#pragma unroll
    for (int rr = 0; rr < 4; ++rr) {
        const int m = wm * 16 + lh * 4 + rr;      // within 64-row tile
        const float bv = bias[mt * 64 + m];
        yb[m * 256 + wn * 32 + lr]      = f2bf(acc0[rr] + bv);
        yb[m * 256 + wn * 32 + 16 + lr] = f2bf(acc1[rr] + bv);
        // wave-local sum over its 32 n positions (fp32, unchanged)
        float s = acc0[rr] + acc1[rr];
        s += __shfl_xor(s, 1);
        s += __shfl_xor(s, 2);
        s += __shfl_xor(s, 4);
        s += __shfl_xor(s, 8);
        if (lr == 0)
            chanpart[(size_t)(b * 512 + mt * 64 + m) * 8 + nq * 2 + wn] = s + 32.f * bv;
    }
}

// Per (bg, p-chunk of 32): fc1+fc2 (redundant per chunk, cheap), sa dot over
// 256 channels, deterministic gsum partial.  512 blocks x 256 threads.
// y4 is bf16; slice staged into LDS as fp32.
__global__ __launch_bounds__(256) void sa_kernel(
    const unsigned short* __restrict__ y4, const float* __restrict__ chanpart,
    const float* __restrict__ fc1w, const float* __restrict__ fc1b,
    const float* __restrict__ fc2w, const float* __restrict__ fc2b,
    const float* __restrict__ saw, const float* __restrict__ sab,
    float* __restrict__ ca, float* __restrict__ sa, float* __restrict__ gsums)
{
    const int blk = blockIdx.x;
    const int bg = blk >> 3, pc = blk & 7;
    const int b = bg >> 3, g = bg & 7;
    const int tid = threadIdx.x;
    const unsigned short* xg = y4 + ((size_t)b * 512 + (g & 1) * 256) * 256 + pc * 32;

    __shared__ float xl[256][32];
    __shared__ float avgs[256], red[256], hs[64], cas[256], caws[256], sas[32];

    // stage y4 slice [256c][32p] (bf16 -> fp32)
#pragma unroll
    for (int i = 0; i < 4; ++i) {
        int f = i * 256 + tid;            // ushort8 chunk id, 1024 total
        int c = f >> 2, jj = f & 3;
        u16x8 v = *(const u16x8*)(xg + c * 256 + jj * 8);
#pragma unroll
        for (int e = 0; e < 8; ++e) xl[c][jj * 8 + e] = bf2f(v[e]);
    }
    {
        const float* cpp = chanpart + (size_t)(b * 512 + (g & 1) * 256 + tid) * 8;
        float cp = 0.f;
#pragma unroll
        for (int i = 0; i < 8; ++i) cp += cpp[i];
        avgs[tid] = cp * (1.f / 256.f);
    }
    __syncthreads();
    // fc1: 256 -> 64, relu
    {
        int o = tid & 63, seg = tid >> 6;
        const float* wr = fc1w + (g * 64 + o) * 256 + seg * 64;
        const float* av = avgs + seg * 64;
        float s = 0.f;
#pragma unroll
        for (int i = 0; i < 64; ++i) s = fmaf(av[i], wr[i], s);
        red[tid] = s;
    }
    __syncthreads();
    if (tid < 64) {
        float s = fc1b[g * 64 + tid] + red[tid] + red[64 + tid] + red[128 + tid] + red[192 + tid];
        hs[tid] = fmaxf(s, 0.f);
    }
    __syncthreads();
    // fc2: 64 -> 256, sigmoid
    {
        const float* wr = fc2w + (g * 256 + tid) * 64;
        float s = fc2b[g * 256 + tid];
#pragma unroll
        for (int i = 0; i < 64; ++i) s = fmaf(hs[i], wr[i], s);
        float v = sigmoidf_(s);
        cas[tid] = v;
        caws[tid] = v * saw[g * 256 + tid];
        if (pc == 0) ca[bg * 256 + tid] = v;
    }
    __syncthreads();
    // sa dot over channels for 32 positions (from LDS)
    const int p_l = tid & 31, seg8 = tid >> 5;
    {
        float s = 0.f;
#pragma unroll
        for (int i = 0; i < 32; ++i) {
            int c = seg8 * 32 + i;
            s = fmaf(xl[c][p_l], caws[c], s);
        }
        red[tid] = s;
    }
    __syncthreads();
    if (tid < 32) {
        float s = sab[g];
#pragma unroll
        for (int k = 0; k < 8; ++k) s += red[k * 32 + tid];
        float v = sigmoidf_(s);
        sas[tid] = v;
        sa[bg * 256 + pc * 32 + tid] = v;
    }
    __syncthreads();
    // gsum partial: sum sigmoid(x*ca*sa) over this chunk's 32p x 256c
    {
        float sv = sas[p_l];
        float s = 0.f;
#pragma unroll
        for (int i = 0; i < 32; ++i) {
            int c = seg8 * 32 + i;
            s += sigmoidf_(xl[c][p_l] * cas[c] * sv);
        }
        red[tid] = s;
    }
    __syncthreads();
    for (int off = 128; off > 0; off >>= 1) {
        if (tid < off) red[tid] += red[tid + off];
        __syncthreads();
    }
    if (tid == 0) gsums[blk] = red[0];
}

// out = x*(1+mask); mask = (y>mean)?1:y, y = sigmoid(x*ca*sa).
// Dedup: each y4 element (bf16) read ONCE, expanded to its 4 output channels
// (g = parity, parity+2, parity+4, parity+6).  262144 threads total.
__global__ __launch_bounds__(256) void final_kernel(
    const unsigned short* __restrict__ y4, const float* __restrict__ ca,
    const float* __restrict__ sa, const float* __restrict__ gsums,
    float* __restrict__ out)
{
    int f = blockIdx.x * 256 + threadIdx.x;   // 0..262143: (b, c', p4)
    int p4 = f & 63;                          // quad index within row
    int cp = (f >> 6) & 511;                  // unique y4 channel 0..511
    int b  = f >> 15;                         // batch 0..7
    int par = cp >> 8, c = cp & 255;
    const ushort4 xu = *(const ushort4*)(y4 + ((size_t)b * 512 + cp) * 256 + p4 * 4);
    const float x0 = bf2f(xu.x), x1 = bf2f(xu.y), x2 = bf2f(xu.z), x3 = bf2f(xu.w);
#pragma unroll
    for (int gg = 0; gg < 4; ++gg) {
        const int g = par + gg * 2;
        const int bg = b * 8 + g;
        const float cav = ca[bg * 256 + c];
        const float4 sv = *(const float4*)(sa + bg * 256 + p4 * 4);
        float msum = 0.f;
#pragma unroll
        for (int i = 0; i < 8; ++i) msum += gsums[bg * 8 + i];
        const float mean = msum * (1.f / 65536.f);
        float4 o;
#define DOLANE(OX, XV, SX) { float yv = sigmoidf_((XV) * cav * sv.SX); \
        float mk = (yv > mean) ? 1.f : yv; o.OX = (XV) * (1.f + mk); }
        DOLANE(x, x0, x) DOLANE(y, x1, y) DOLANE(z, x2, z) DOLANE(w, x3, w)
#undef DOLANE
        *(float4*)(out + ((size_t)b * 2048 + g * 256 + c) * 256 + p4 * 4) = o;
    }
}

extern "C" void kernel_launch(void* const* d_in, const int* in_sizes, int n_in,
                              void* d_out, int out_size, void* d_ws, size_t ws_size,
                              hipStream_t stream) {
    const float* x4   = (const float*)d_in[3];
    const float* w4   = (const float*)d_in[10];
    const float* b4   = (const float*)d_in[11];
    const float* fc1w = (const float*)d_in[12];
    const float* fc1b = (const float*)d_in[13];
    const float* fc2w = (const float*)d_in[14];
    const float* fc2b = (const float*)d_in[15];
    const float* saw  = (const float*)d_in[16];
    const float* sab  = (const float*)d_in[17];
    float* out = (float*)d_out;

    float* ws = (float*)d_ws;
    unsigned short* y4 = (unsigned short*)ws;  // 1048576 bf16 (= 524288 floats)
    float* ca       = ws + 524288;           // 16384
    float* saBuf    = ws + 540672;           // 16384
    float* gsums    = ws + 557056;           // 512
    float* chanpart = ws + 557568;           // 32768

    gemm_fused<<<dim3(256), dim3(512), 0, stream>>>(x4, w4, b4, y4, chanpart);
    sa_kernel<<<dim3(512), dim3(256), 0, stream>>>(y4, chanpart, fc1w, fc1b, fc2w, fc2b,
                                                   saw, sab, ca, saBuf, gsums);
    final_kernel<<<dim3(1024), dim3(256), 0, stream>>>(y4, ca, saBuf, gsums, out);
}